// Round 1
// baseline (15673.128 us; speedup 1.0000x reference)
//
#include <hip/hip_runtime.h>
#include <stdint.h>

#define T_STEPS 2048
#define NBATCH  64
#define DIN     256
#define HID     512
#define NCOL    2048     // 4*HID
#define KTOT    768      // DIN + HID
#define LDK     776      // padded z row stride (bf16 elems) -> 2-way-max bank alias
#define NGRP    8        // groups, one per XCD (blockIdx % 8)
#define BPG     32       // blocks per group (j-slices of 16)
#define MROW    8        // batches per group

#define FLAGS_DWORDS ((size_t)(T_STEPS + 1) * NGRP * BPG)   // [t][g][p]
#define HBUF_DWORDS  ((size_t)2 * NBATCH * HID / 2)          // bf16 pairs, double buffer
#define WS_DWORDS    (FLAGS_DWORDS + HBUF_DWORDS)

typedef __attribute__((ext_vector_type(8))) short bf16x8;
typedef __attribute__((ext_vector_type(4))) float f32x4;

__device__ __forceinline__ ushort f2bf(float f) {
    union { float f; uint32_t u; } v; v.f = f;
    uint32_t r = v.u + 0x7FFFu + ((v.u >> 16) & 1u);   // RNE
    return (ushort)(r >> 16);
}
__device__ __forceinline__ float sigm(float x) { return 1.f / (1.f + __expf(-x)); }
__device__ __forceinline__ float tanh_fast(float x) {
    float a = fabsf(x);
    float e = __expf(-2.f * a);          // in (0,1], no overflow
    float t = (1.f - e) / (1.f + e);
    return x < 0.f ? -t : t;
}

__global__ void zero_ws_kernel(uint32_t* w, size_t n) {
    size_t i = (size_t)blockIdx.x * blockDim.x + threadIdx.x;
    if (i < n) w[i] = 0u;
}

__global__ __launch_bounds__(256, 1) void lstm_persist(
    const float* __restrict__ x,     // [T][B][D]
    const float* __restrict__ Wx,    // [D][4H]
    const float* __restrict__ Wh,    // [H][4H]
    const float* __restrict__ bias,  // [4H]
    float* __restrict__ out,         // ys [T][B][H] + hT [B][H] + cT [B][H]
    uint32_t* __restrict__ flags,    // [T+1][NGRP][BPG]
    uint32_t* __restrict__ hbuf)     // [2][B][H] as bf16 pairs
{
    __shared__ __align__(16) ushort zlds[16][LDK];   // z = [x_t ; h_t] bf16, rows 8..15 zero
    __shared__ float  gex[4][8][16];                 // gate exchange (i,f,g,o)
    __shared__ __align__(4) ushort hst[8][16];       // h_next staging (bf16)

    const int tid  = threadIdx.x;          // 256 threads = 4 waves
    const int gid  = blockIdx.x & 7;       // group / XCD
    const int p    = blockIdx.x >> 3;      // block-in-group, 0..31
    const int j0   = p * 16;               // hidden-column slice base
    const int gb   = gid * MROW;           // batch base
    const int wave = tid >> 6;             // gate index: 0=i 1=f 2=g 3=o
    const int lane = tid & 63;

    // ---- init: zero the padding rows of z (A-frag rows 8..15 -> zero gates there)
    for (int i = tid; i < 8 * LDK; i += 256) zlds[8 + i / LDK][i % LDK] = 0;

    // ---- weight slice -> registers. wave w, lane l holds B[k][col] for
    // col = w*512 + j0 + (l&15), k = 32*ch + 8*(l>>4) + e  (exact MFMA B layout)
    bf16x8 wreg[24];
    {
        const int col   = wave * HID + j0 + (lane & 15);
        const int kbase = (lane >> 4) * 8;
        #pragma unroll
        for (int ch = 0; ch < 24; ++ch) {
            bf16x8 w;
            #pragma unroll
            for (int e = 0; e < 8; ++e) {
                int k = ch * 32 + kbase + e;
                float wv = (k < DIN) ? Wx[(size_t)k * NCOL + col]
                                     : Wh[(size_t)(k - DIN) * NCOL + col];
                w[e] = (short)f2bf(wv);
            }
            wreg[ch] = w;
        }
    }
    const float biasv = bias[wave * HID + j0 + (lane & 15)];
    float creg = 0.f;                       // c state: tid<128 owns (b=tid>>4, j=tid&15)
    __syncthreads();

    const int xr = tid >> 5;                // staging row 0..7
    const int xc = (tid & 31) * 8;          // 8 elems per thread

    const int arow = lane & 15;
    const int koff = (lane >> 4) * 8;
    const ushort* za = &zlds[arow][0];

    for (int t = 0; t < T_STEPS; ++t) {
        // ---- stage x_t (independent of h; overlaps peers' previous step)
        {
            const float* xp = x + ((size_t)t * NBATCH + gb + xr) * DIN + xc;
            float4 v0 = *(const float4*)xp;
            float4 v1 = *(const float4*)(xp + 4);
            uint4 pk;
            pk.x = (uint32_t)f2bf(v0.x) | ((uint32_t)f2bf(v0.y) << 16);
            pk.y = (uint32_t)f2bf(v0.z) | ((uint32_t)f2bf(v0.w) << 16);
            pk.z = (uint32_t)f2bf(v1.x) | ((uint32_t)f2bf(v1.y) << 16);
            pk.w = (uint32_t)f2bf(v1.z) | ((uint32_t)f2bf(v1.w) << 16);
            *(uint4*)&zlds[xr][xc] = pk;
        }
        __syncthreads();

        // ---- x-part MFMAs (K = 0..255) while waiting on peers
        f32x4 acc = {0.f, 0.f, 0.f, 0.f};
        #pragma unroll
        for (int ch = 0; ch < 8; ++ch) {
            bf16x8 af = *(const bf16x8*)(za + ch * 32 + koff);
            acc = __builtin_amdgcn_mfma_f32_16x16x32_bf16(af, wreg[ch], acc, 0, 0, 0);
        }

        // ---- wait for h_t from all 32 producers of this group
        if (t > 0 && tid < BPG) {
            const uint32_t* fp = &flags[((size_t)t * NGRP + gid) * BPG + tid];
            int guard = 0;
            while (__hip_atomic_load(fp, __ATOMIC_RELAXED, __HIP_MEMORY_SCOPE_AGENT) == 0u) {
                if (++guard > (1 << 14)) break;      // hang-safety; never hit in practice
                __builtin_amdgcn_s_sleep(1);
            }
            (void)__hip_atomic_load(fp, __ATOMIC_ACQUIRE, __HIP_MEMORY_SCOPE_AGENT); // L1/L2 inv
        }
        __syncthreads();

        // ---- stage h_t (bf16, 8 KB) into z cols 256..767
        {
            const uint32_t* hp = hbuf + ((size_t)(t & 1) * NBATCH + gb + xr) * (HID / 2)
                                 + (size_t)(tid & 31) * 8;
            uint4 h0 = *(const uint4*)hp;
            uint4 h1 = *(const uint4*)(hp + 4);
            *(uint4*)&zlds[xr][DIN + (tid & 31) * 16]     = h0;
            *(uint4*)&zlds[xr][DIN + (tid & 31) * 16 + 8] = h1;
        }
        __syncthreads();

        // ---- h-part MFMAs (K = 256..767)
        #pragma unroll
        for (int ch = 8; ch < 24; ++ch) {
            bf16x8 af = *(const bf16x8*)(za + ch * 32 + koff);
            acc = __builtin_amdgcn_mfma_f32_16x16x32_bf16(af, wreg[ch], acc, 0, 0, 0);
        }

        // ---- exchange gates: acc row=(lane>>4)*4+r (batch), col=lane&15 (j)
        if (lane < 32) {
            int r0 = (lane >> 4) * 4;
            #pragma unroll
            for (int r = 0; r < 4; ++r)
                gex[wave][r0 + r][lane & 15] = acc[r] + biasv;
        }
        __syncthreads();

        // ---- elementwise LSTM cell update
        if (tid < 128) {
            int b = tid >> 4, j = tid & 15;
            float iv = sigm(gex[0][b][j]);
            float fv = sigm(gex[1][b][j]);
            float gv = tanh_fast(gex[2][b][j]);
            float ov = sigm(gex[3][b][j]);
            creg = fv * creg + iv * gv;
            float hv = ov * tanh_fast(creg);
            hst[b][j] = f2bf(hv);
            float* yp = out + ((size_t)t * NBATCH + gb + b) * HID + j0 + j;
            __builtin_nontemporal_store(hv, yp);            // streaming: keep L2 clean
            if (t == T_STEPS - 1) {
                float* hTp = out + (size_t)T_STEPS * NBATCH * HID
                             + (size_t)(gb + b) * HID + j0 + j;
                __builtin_nontemporal_store(hv, hTp);
                __builtin_nontemporal_store(creg, hTp + (size_t)NBATCH * HID);
            }
        }
        __syncthreads();

        // ---- publish h_{t+1} slice (512 B) into the other h buffer
        if (tid < 64) {
            int r = tid >> 3, d = tid & 7;
            uint32_t v = (uint32_t)hst[r][d * 2] | ((uint32_t)hst[r][d * 2 + 1] << 16);
            hbuf[((size_t)((t + 1) & 1) * NBATCH + gb + r) * (HID / 2) + (j0 >> 1) + d] = v;
        }
        __syncthreads();   // drains stores (vmcnt 0) before the release flag
        if (tid == 0) {
            __hip_atomic_store(&flags[((size_t)(t + 1) * NGRP + gid) * BPG + p], 1u,
                               __ATOMIC_RELEASE, __HIP_MEMORY_SCOPE_AGENT);
        }
    }
}

extern "C" void kernel_launch(void* const* d_in, const int* in_sizes, int n_in,
                              void* d_out, int out_size, void* d_ws, size_t ws_size,
                              hipStream_t stream) {
    const float* x    = (const float*)d_in[0];
    const float* Wx   = (const float*)d_in[1];
    const float* Wh   = (const float*)d_in[2];
    const float* bias = (const float*)d_in[3];
    float* out = (float*)d_out;

    uint32_t* ws    = (uint32_t*)d_ws;
    uint32_t* flags = ws;                          // [T+1][8][32] -> ~2.1 MB
    uint32_t* hbuf  = ws + FLAGS_DWORDS;           // [2][64][256] dwords -> 128 KB

    // zero flags + h0/c-free state (deterministic each call; graph-capturable)
    {
        size_t n = WS_DWORDS;
        int blocks = (int)((n + 255) / 256);
        zero_ws_kernel<<<dim3(blocks), dim3(256), 0, stream>>>(ws, n);
    }
    lstm_persist<<<dim3(NGRP * BPG), dim3(256), 0, stream>>>(x, Wx, Wh, bias, out, flags, hbuf);
}

// Round 2
// 6965.757 us; speedup vs baseline: 2.2500x; 2.2500x over previous
//
#include <hip/hip_runtime.h>
#include <stdint.h>

#define T_STEPS 2048
#define NBATCH  64
#define DIN     256
#define HID     512
#define NCOL    2048     // 4*HID
#define LDK     776      // padded z row stride (bf16 elems)
#define NGRP    8        // groups, one per XCD (blockIdx % 8)
#define BPG     32       // blocks per group (j-slices of 16)
#define MROW    8        // batches per group

#define CNT_DWORDS  ((size_t)(T_STEPS + 1) * NGRP)          // per-step arrival counters
#define HBUF_DWORDS ((size_t)2 * NBATCH * (HID / 2))        // bf16 pairs, double buffer
#define WS_DWORDS   (CNT_DWORDS + HBUF_DWORDS)

typedef __attribute__((ext_vector_type(8))) short bf16x8;
typedef __attribute__((ext_vector_type(4))) float f32x4;

__device__ __forceinline__ ushort f2bf(float f) {
    union { float f; uint32_t u; } v; v.f = f;
    uint32_t r = v.u + 0x7FFFu + ((v.u >> 16) & 1u);   // RNE
    return (ushort)(r >> 16);
}
__device__ __forceinline__ float sigm(float x) { return 1.f / (1.f + __expf(-x)); }
__device__ __forceinline__ float tanh_fast(float x) {
    float a = fabsf(x);
    float e = __expf(-2.f * a);          // in (0,1], no overflow
    float t = (1.f - e) / (1.f + e);
    return x < 0.f ? -t : t;
}

__global__ void zero_ws_kernel(uint32_t* w, size_t n) {
    size_t i = (size_t)blockIdx.x * blockDim.x + threadIdx.x;
    if (i < n) w[i] = 0u;
}

__global__ __launch_bounds__(256, 1) void lstm_persist(
    const float* __restrict__ x,     // [T][B][D]
    const float* __restrict__ Wx,    // [D][4H]
    const float* __restrict__ Wh,    // [H][4H]
    const float* __restrict__ bias,  // [4H]
    float* __restrict__ out,         // ys [T][B][H] + hT [B][H] + cT [B][H]
    uint32_t* __restrict__ cnt,      // [T+1][NGRP] arrival counters
    uint32_t* __restrict__ hbuf)     // [2][B][H/2] bf16-pair dwords
{
    __shared__ __align__(16) ushort zlds[16][LDK];   // z = [x_t ; h_t] bf16, rows 8..15 zero
    __shared__ float gex[4][8][16];                  // gate exchange (i,f,g,o)

    const int tid  = threadIdx.x;          // 256 threads = 4 waves
    const int gid  = blockIdx.x & 7;       // group / XCD (round-robin dispatch)
    const int p    = blockIdx.x >> 3;      // block-in-group, 0..31
    const int j0   = p * 16;               // hidden-column slice base
    const int gb   = gid * MROW;           // batch base
    const int wave = tid >> 6;             // gate index: 0=i 1=f 2=g 3=o
    const int lane = tid & 63;

    // ---- zero the padding rows of z (A rows 8..15 -> zero gate rows)
    for (int i = tid; i < 8 * LDK; i += 256) zlds[8 + i / LDK][i % LDK] = 0;

    // ---- weight slice -> registers (exact MFMA B layout)
    bf16x8 wreg[24];
    {
        const int col   = wave * HID + j0 + (lane & 15);
        const int kbase = (lane >> 4) * 8;
        #pragma unroll
        for (int ch = 0; ch < 24; ++ch) {
            bf16x8 w;
            #pragma unroll
            for (int e = 0; e < 8; ++e) {
                int k = ch * 32 + kbase + e;
                float wv = (k < DIN) ? Wx[(size_t)k * NCOL + col]
                                     : Wh[(size_t)(k - DIN) * NCOL + col];
                w[e] = (short)f2bf(wv);
            }
            wreg[ch] = w;
        }
    }
    const float biasv = bias[wave * HID + j0 + (lane & 15)];
    // c state: tid<64 owns (b = tid>>3, j = j0 + 2*(tid&7) + {0,1})
    float c0 = 0.f, c1 = 0.f;
    __syncthreads();

    const int xr = tid >> 5;                // staging row 0..7
    const int xc = (tid & 31) * 8;          // 8 x-elems per thread

    const int arow = lane & 15;
    const int koff = (lane >> 4) * 8;
    const ushort* za = &zlds[arow][0];

    for (int t = 0; t < T_STEPS; ++t) {
        // ---- stage x_t (overlaps peers finishing previous step)
        {
            const float* xp = x + ((size_t)t * NBATCH + gb + xr) * DIN + xc;
            float4 v0 = *(const float4*)xp;
            float4 v1 = *(const float4*)(xp + 4);
            uint4 pk;
            pk.x = (uint32_t)f2bf(v0.x) | ((uint32_t)f2bf(v0.y) << 16);
            pk.y = (uint32_t)f2bf(v0.z) | ((uint32_t)f2bf(v0.w) << 16);
            pk.z = (uint32_t)f2bf(v1.x) | ((uint32_t)f2bf(v1.y) << 16);
            pk.w = (uint32_t)f2bf(v1.z) | ((uint32_t)f2bf(v1.w) << 16);
            *(uint4*)&zlds[xr][xc] = pk;
        }
        __syncthreads();                                   // bar1

        // ---- x-part MFMAs (K = 0..255) — overlaps the wait below
        f32x4 a0 = {0.f, 0.f, 0.f, 0.f};
        f32x4 a1 = {0.f, 0.f, 0.f, 0.f};
        f32x4 a2 = {0.f, 0.f, 0.f, 0.f};
        #pragma unroll
        for (int ch = 0; ch < 8; ++ch) {
            bf16x8 af = *(const bf16x8*)(za + ch * 32 + koff);
            a0 = __builtin_amdgcn_mfma_f32_16x16x32_bf16(af, wreg[ch], a0, 0, 0, 0);
        }

        // ---- single-poller wait: all 32 producers of this group arrived
        if (t > 0 && tid == 0) {
            const uint32_t* cp = &cnt[(size_t)t * NGRP + gid];
            int guard = 0;
            while (__hip_atomic_load(cp, __ATOMIC_RELAXED, __HIP_MEMORY_SCOPE_AGENT) < (uint32_t)BPG) {
                if (++guard > (1 << 16)) break;            // hang safety
            }
        }
        __syncthreads();                                   // bar2

        // ---- stage h_t via coherent (sc1) relaxed atomic loads -> LDS
        {
            const uint32_t* hp = hbuf + ((size_t)(t & 1) * NBATCH + gb + xr) * (HID / 2)
                                 + (size_t)(tid & 31) * 8;
            uint32_t v[8];
            #pragma unroll
            for (int e = 0; e < 8; ++e)
                v[e] = __hip_atomic_load(hp + e, __ATOMIC_RELAXED, __HIP_MEMORY_SCOPE_AGENT);
            uint4 q0 = {v[0], v[1], v[2], v[3]};
            uint4 q1 = {v[4], v[5], v[6], v[7]};
            *(uint4*)&zlds[xr][DIN + (tid & 31) * 16]     = q0;
            *(uint4*)&zlds[xr][DIN + (tid & 31) * 16 + 8] = q1;
        }
        __syncthreads();                                   // bar3

        // ---- h-part MFMAs (K = 256..767), two independent chains
        #pragma unroll
        for (int ch = 8; ch < 16; ++ch) {
            bf16x8 af = *(const bf16x8*)(za + ch * 32 + koff);
            a1 = __builtin_amdgcn_mfma_f32_16x16x32_bf16(af, wreg[ch], a1, 0, 0, 0);
        }
        #pragma unroll
        for (int ch = 16; ch < 24; ++ch) {
            bf16x8 af = *(const bf16x8*)(za + ch * 32 + koff);
            a2 = __builtin_amdgcn_mfma_f32_16x16x32_bf16(af, wreg[ch], a2, 0, 0, 0);
        }
        f32x4 acc = a0 + a1;
        acc = acc + a2;

        // ---- gate exchange: acc row=(lane>>4)*4+r (batch), col=lane&15 (j)
        if (lane < 32) {
            int r0 = (lane >> 4) * 4;
            #pragma unroll
            for (int r = 0; r < 4; ++r)
                gex[wave][r0 + r][lane & 15] = acc[r] + biasv;
        }
        __syncthreads();                                   // bar4

        // ---- wave 0: cell update + publish; waves 1-3 fall through to stage x_{t+1}
        if (tid < 64) {
            const int b  = tid >> 3;
            const int jp = tid & 7;
            const int j  = jp * 2;
            float i0 = sigm(gex[0][b][j]),     i1 = sigm(gex[0][b][j + 1]);
            float f0 = sigm(gex[1][b][j]),     f1 = sigm(gex[1][b][j + 1]);
            float g0 = tanh_fast(gex[2][b][j]), g1 = tanh_fast(gex[2][b][j + 1]);
            float o0 = sigm(gex[3][b][j]),     o1 = sigm(gex[3][b][j + 1]);
            c0 = f0 * c0 + i0 * g0;
            c1 = f1 * c1 + i1 * g1;
            float h0v = o0 * tanh_fast(c0);
            float h1v = o1 * tanh_fast(c1);

            // publish h_{t+1} slice first (coherent dword), so vmcnt covers it
            uint32_t pk = (uint32_t)f2bf(h0v) | ((uint32_t)f2bf(h1v) << 16);
            __hip_atomic_store(hbuf + ((size_t)((t + 1) & 1) * NBATCH + gb + b) * (HID / 2)
                               + (j0 >> 1) + jp,
                               pk, __ATOMIC_RELAXED, __HIP_MEMORY_SCOPE_AGENT);

            // ys output (plain store: acks at L2, drains lazily)
            float2 hv = {h0v, h1v};
            *(float2*)(out + ((size_t)t * NBATCH + gb + b) * HID + j0 + j) = hv;
            if (t == T_STEPS - 1) {
                float* hTp = out + (size_t)T_STEPS * NBATCH * HID
                             + (size_t)(gb + b) * HID + j0 + j;
                float2 cv = {c0, c1};
                *(float2*)hTp = hv;
                *(float2*)(hTp + (size_t)NBATCH * HID) = cv;
            }

            // wave-level store drain, then one arrival tick (lane 0)
            asm volatile("s_waitcnt vmcnt(0)" ::: "memory");
            if (tid == 0)
                __hip_atomic_fetch_add(&cnt[(size_t)(t + 1) * NGRP + gid], 1u,
                                       __ATOMIC_RELAXED, __HIP_MEMORY_SCOPE_AGENT);
        }
        // no barrier: waves 1-3 proceed to stage x_{t+1}; bar1 re-syncs
    }
}

extern "C" void kernel_launch(void* const* d_in, const int* in_sizes, int n_in,
                              void* d_out, int out_size, void* d_ws, size_t ws_size,
                              hipStream_t stream) {
    const float* x    = (const float*)d_in[0];
    const float* Wx   = (const float*)d_in[1];
    const float* Wh   = (const float*)d_in[2];
    const float* bias = (const float*)d_in[3];
    float* out = (float*)d_out;

    uint32_t* ws   = (uint32_t*)d_ws;
    uint32_t* cnt  = ws;                           // [T+1][8] counters (~64 KB)
    uint32_t* hbuf = ws + CNT_DWORDS;              // [2][64][256] dwords (128 KB)

    {
        size_t n = WS_DWORDS;
        int blocks = (int)((n + 255) / 256);
        zero_ws_kernel<<<dim3(blocks), dim3(256), 0, stream>>>(ws, n);
    }
    lstm_persist<<<dim3(NGRP * BPG), dim3(256), 0, stream>>>(x, Wx, Wh, bias, out, cnt, hbuf);
}

// Round 4
// 5277.864 us; speedup vs baseline: 2.9696x; 1.3198x over previous
//
#include <hip/hip_runtime.h>
#include <stdint.h>

#define T_STEPS 2048
#define NBATCH  64
#define DIN     256
#define HID     512
#define NCOL    2048     // 4*HID
#define LDK     776      // padded z row stride (bf16 elems)
#define NGRP    8        // groups, one per XCD (blockIdx % 8)
#define BPG     32       // blocks per group (j-slices of 16)
#define MROW    8        // batches per group

#define FLAGS_DWORDS ((size_t)(T_STEPS + 1) * NGRP * BPG)   // [t][g][p]
#define HBUF_DWORDS  ((size_t)2 * NBATCH * (HID / 2))       // packed bf16 pairs, dbuf
#define WS_DWORDS    (FLAGS_DWORDS + HBUF_DWORDS)

typedef __attribute__((ext_vector_type(8))) short bf16x8;
typedef __attribute__((ext_vector_type(4))) float f32x4;

static __device__ __forceinline__ ushort f2bf(float f) {
    union { float f; uint32_t u; } v; v.f = f;
    uint32_t r = v.u + 0x7FFFu + ((v.u >> 16) & 1u);   // RNE
    return (ushort)(r >> 16);
}
static __device__ __forceinline__ float sigm(float x) { return 1.f / (1.f + __expf(-x)); }
static __device__ __forceinline__ float tanh_fast(float x) {
    float a = fabsf(x);
    float e = __expf(-2.f * a);
    float t = (1.f - e) / (1.f + e);
    return x < 0.f ? -t : t;
}

// Coherent (L1/L2-bypass) loads: travel via Infinity Cache, point-coherent
// across XCDs. Payload validity is ordered by the flag protocol.
static __device__ __forceinline__ uint32_t ld_dw_sc(const uint32_t* p) {
    uint32_t v;
    asm volatile("global_load_dword %0, %1, off sc0 sc1" : "=v"(v) : "v"(p) : "memory");
    return v;
}
static __device__ __forceinline__ uint4 ld_dwx4_sc(const uint32_t* p) {
    uint4 v;
    asm volatile("global_load_dwordx4 %0, %1, off sc0 sc1" : "=v"(v) : "v"(p) : "memory");
    return v;
}
static __device__ __forceinline__ uint4 ld_dwx4_pl(const void* p) {   // plain cached
    uint4 v;
    asm volatile("global_load_dwordx4 %0, %1, off" : "=v"(v) : "v"(p) : "memory");
    return v;
}
static __device__ __forceinline__ void wait_vm0() {
    asm volatile("s_waitcnt vmcnt(0)" ::: "memory");
    __builtin_amdgcn_sched_barrier(0);
}
// vmcnt retires OLDEST-first: with issue order [h0, h1, xa, xb], vmcnt(2)
// guarantees h0/h1 complete while the two x-prefetch loads stay in flight.
static __device__ __forceinline__ void wait_vm2() {
    asm volatile("s_waitcnt vmcnt(2)" ::: "memory");
    __builtin_amdgcn_sched_barrier(0);
}

__global__ void zero_ws_kernel(uint32_t* w, size_t n) {
    size_t i = (size_t)blockIdx.x * blockDim.x + threadIdx.x;
    if (i < n) w[i] = 0u;
}

__global__ __launch_bounds__(256, 1) void lstm_persist(
    const float* __restrict__ x,     // [T][B][D]
    const float* __restrict__ Wx,    // [D][4H]
    const float* __restrict__ Wh,    // [H][4H]
    const float* __restrict__ bias,  // [4H]
    float* __restrict__ out,         // ys [T][B][H] + hT [B][H] + cT [B][H]
    uint32_t* __restrict__ flags,    // [T+1][NGRP][BPG] (pre-zeroed)
    uint32_t* __restrict__ hbuf)     // [2][B][H/2] packed bf16 pairs
{
    __shared__ __align__(16) ushort zlds[16][LDK];   // z = [x_t ; h_t], rows 8..15 zero
    __shared__ __align__(16) float gex[8][17][4];    // [batch][j(+pad)][gate i,f,g,o]

    const int tid  = threadIdx.x;          // 256 threads = 4 waves
    const int gid  = blockIdx.x & 7;       // group / XCD
    const int p    = blockIdx.x >> 3;      // block-in-group
    const int j0   = p * 16;
    const int gb   = gid * MROW;
    const int wave = tid >> 6;             // gate index
    const int lane = tid & 63;

    for (int i = tid; i < 8 * LDK; i += 256) zlds[8 + i / LDK][i % LDK] = 0;

    // weight slice -> registers (MFMA B layout)
    bf16x8 wreg[24];
    {
        const int col   = wave * HID + j0 + (lane & 15);
        const int kbase = (lane >> 4) * 8;
        #pragma unroll
        for (int ch = 0; ch < 24; ++ch) {
            bf16x8 w;
            #pragma unroll
            for (int e = 0; e < 8; ++e) {
                int k = ch * 32 + kbase + e;
                float wv = (k < DIN) ? Wx[(size_t)k * NCOL + col]
                                     : Wh[(size_t)(k - DIN) * NCOL + col];
                w[e] = (short)f2bf(wv);
            }
            wreg[ch] = w;
        }
    }
    const float biasv = bias[wave * HID + j0 + (lane & 15)];
    float c0 = 0.f, c1 = 0.f;               // c state: wave0, b=tid>>3, j=2*(tid&7)+{0,1}
    __syncthreads();

    const int xr   = tid >> 5;              // x staging row
    const int xc   = (tid & 31) * 8;        // 8 x-elems / thread
    const int arow = lane & 15;
    const int koff = (lane >> 4) * 8;
    const ushort* za = &zlds[arow][0];
    const int hr = wave * 2;                // h-load rows: hr, hr+1 (lane-consecutive dwords)

    // x prefetch for t=0
    uint4 xa, xb;
    {
        const float* xp = x + ((size_t)0 * NBATCH + gb + xr) * DIN + xc;
        xa = ld_dwx4_pl(xp);
        xb = ld_dwx4_pl(xp + 4);
    }

    for (int t = 0; t < T_STEPS; ++t) {
        // x regs ready (wave0 t>0: already drained by update's vmcnt(0))
        if (t == 0 || wave != 0) wait_vm0();
        else __builtin_amdgcn_sched_barrier(0);

        // pack x_t (bf16) -> LDS
        {
            uint4 pk;
            pk.x = (uint32_t)f2bf(__uint_as_float(xa.x)) | ((uint32_t)f2bf(__uint_as_float(xa.y)) << 16);
            pk.y = (uint32_t)f2bf(__uint_as_float(xa.z)) | ((uint32_t)f2bf(__uint_as_float(xa.w)) << 16);
            pk.z = (uint32_t)f2bf(__uint_as_float(xb.x)) | ((uint32_t)f2bf(__uint_as_float(xb.y)) << 16);
            pk.w = (uint32_t)f2bf(__uint_as_float(xb.z)) | ((uint32_t)f2bf(__uint_as_float(xb.w)) << 16);
            *(uint4*)&zlds[xr][xc] = pk;
        }
        __syncthreads();                                   // bar1

        // x-part MFMAs (K = 0..255), overlaps flag wait
        f32x4 a0 = {0.f, 0.f, 0.f, 0.f};
        f32x4 a1 = {0.f, 0.f, 0.f, 0.f};
        f32x4 a2 = {0.f, 0.f, 0.f, 0.f};
        #pragma unroll
        for (int ch = 0; ch < 8; ++ch) {
            bf16x8 af = *(const bf16x8*)(za + ch * 32 + koff);
            a0 = __builtin_amdgcn_mfma_f32_16x16x32_bf16(af, wreg[ch], a0, 0, 0, 0);
        }

        // every wave polls all 32 producer flags (lanes 32..63 mirror 0..31)
        if (t > 0) {
            const uint32_t* fb = flags + ((size_t)t * NGRP + gid) * BPG + (lane & 31);
            int guard = 0;
            while (true) {
                uint32_t f = ld_dw_sc(fb);
                wait_vm0();
                if (__all(f != 0u)) break;
                if (++guard > 65536) break;                // hang safety
            }
        }

        // h-data loads FIRST (oldest -> retired by vmcnt(2)) ...
        const uint32_t* hb0 = hbuf + ((size_t)(t & 1) * NBATCH + gb + hr) * (HID / 2) + 4 * lane;
        uint4 h0 = ld_dwx4_sc(hb0);
        uint4 h1 = ld_dwx4_sc(hb0 + (HID / 2));
        // ... then x prefetch (t+1) as the two newest, which keep flying
        {
            int tn = (t + 1 < T_STEPS) ? t + 1 : t;
            const float* xp = x + ((size_t)tn * NBATCH + gb + xr) * DIN + xc;
            xa = ld_dwx4_pl(xp);
            xb = ld_dwx4_pl(xp + 4);
        }
        wait_vm2();                                        // h0/h1 done, xa/xb in flight
        *(uint4*)&zlds[hr][DIN + 8 * lane]     = h0;
        *(uint4*)&zlds[hr + 1][DIN + 8 * lane] = h1;
        __syncthreads();                                   // bar3

        // h-part MFMAs (K = 256..767), two chains
        #pragma unroll
        for (int ch = 8; ch < 16; ++ch) {
            bf16x8 af = *(const bf16x8*)(za + ch * 32 + koff);
            a1 = __builtin_amdgcn_mfma_f32_16x16x32_bf16(af, wreg[ch], a1, 0, 0, 0);
        }
        #pragma unroll
        for (int ch = 16; ch < 24; ++ch) {
            bf16x8 af = *(const bf16x8*)(za + ch * 32 + koff);
            a2 = __builtin_amdgcn_mfma_f32_16x16x32_bf16(af, wreg[ch], a2, 0, 0, 0);
        }
        f32x4 acc = (a0 + a1) + a2;

        // gate exchange: acc row=(lane>>4)*4+r (batch), col=lane&15 (j)
        if (lane < 32) {
            int r0 = (lane >> 4) * 4, col = lane & 15;
            #pragma unroll
            for (int r = 0; r < 4; ++r)
                gex[r0 + r][col][wave] = acc[r] + biasv;
        }
        __syncthreads();                                   // bar4

        // wave 0: cell update + publish + release flag
        if (tid < 64) {
            const int b = tid >> 3, jp = tid & 7, j = jp * 2;
            f32x4 ga = *(const f32x4*)&gex[b][j][0];
            f32x4 gc = *(const f32x4*)&gex[b][j + 1][0];
            float i0 = sigm(ga[0]), f0 = sigm(ga[1]), g0 = tanh_fast(ga[2]), o0 = sigm(ga[3]);
            float i1 = sigm(gc[0]), f1 = sigm(gc[1]), g1 = tanh_fast(gc[2]), o1 = sigm(gc[3]);
            c0 = f0 * c0 + i0 * g0;
            c1 = f1 * c1 + i1 * g1;
            float h0v = o0 * tanh_fast(c0);
            float h1v = o1 * tanh_fast(c1);

            uint32_t pkh = (uint32_t)f2bf(h0v) | ((uint32_t)f2bf(h1v) << 16);
            __hip_atomic_store(hbuf + ((size_t)((t + 1) & 1) * NBATCH + gb + b) * (HID / 2)
                               + (j0 >> 1) + jp, pkh,
                               __ATOMIC_RELAXED, __HIP_MEMORY_SCOPE_AGENT);

            float2 hv = {h0v, h1v};
            *(float2*)(out + ((size_t)t * NBATCH + gb + b) * HID + j0 + j) = hv;
            if (t == T_STEPS - 1) {
                float* hTp = out + (size_t)T_STEPS * NBATCH * HID
                             + (size_t)(gb + b) * HID + j0 + j;
                float2 cv = {c0, c1};
                *(float2*)hTp = hv;
                *(float2*)(hTp + (size_t)NBATCH * HID) = cv;
            }

            asm volatile("s_waitcnt vmcnt(0)" ::: "memory");   // data at IF before flag
            if (tid == 0)
                __hip_atomic_store(flags + ((size_t)(t + 1) * NGRP + gid) * BPG + p, 1u,
                                   __ATOMIC_RELAXED, __HIP_MEMORY_SCOPE_AGENT);
        }
        // no trailing barrier: bar1 re-syncs
    }
}

extern "C" void kernel_launch(void* const* d_in, const int* in_sizes, int n_in,
                              void* d_out, int out_size, void* d_ws, size_t ws_size,
                              hipStream_t stream) {
    const float* x    = (const float*)d_in[0];
    const float* Wx   = (const float*)d_in[1];
    const float* Wh   = (const float*)d_in[2];
    const float* bias = (const float*)d_in[3];
    float* out = (float*)d_out;

    uint32_t* ws    = (uint32_t*)d_ws;
    uint32_t* flags = ws;                          // ~2.1 MB
    uint32_t* hbuf  = ws + FLAGS_DWORDS;           // 128 KB

    {
        size_t n = WS_DWORDS;
        int blocks = (int)((n + 255) / 256);
        zero_ws_kernel<<<dim3(blocks), dim3(256), 0, stream>>>(ws, n);
    }
    lstm_persist<<<dim3(NGRP * BPG), dim3(256), 0, stream>>>(x, Wx, Wh, bias, out, flags, hbuf);
}

// Round 6
// 3669.764 us; speedup vs baseline: 4.2709x; 1.4382x over previous
//
#include <hip/hip_runtime.h>
#include <stdint.h>

#define T_STEPS 2048
#define NBATCH  64
#define DIN     256
#define HID     512
#define NCOL    2048     // 4*HID
#define LDK     776      // padded z row stride (bf16 elems)
#define NGRP    8        // groups (blockIdx & 7)
#define BPG     32       // blocks per group (j-slices of 16)
#define MROW    8        // batches per group
#define SENT    0xFFFFFFFFu   // impossible packed-bf16-pair for h in (-1,1)

#define HBUF_DWORDS ((size_t)4 * NBATCH * (HID / 2))   // quad-buffered h exchange

typedef __attribute__((ext_vector_type(8))) short bf16x8;
typedef __attribute__((ext_vector_type(4))) float f32x4;

static __device__ __forceinline__ ushort f2bf(float f) {
    union { float f; uint32_t u; } v; v.f = f;
    uint32_t r = v.u + 0x7FFFu + ((v.u >> 16) & 1u);   // RNE
    return (ushort)(r >> 16);
}
static __device__ __forceinline__ float sigm(float x) { return 1.f / (1.f + __expf(-x)); }
static __device__ __forceinline__ float tanh_fast(float x) {
    float a = fabsf(x);
    float e = __expf(-2.f * a);
    float t = (1.f - e) / (1.f + e);
    return x < 0.f ? -t : t;
}

// R4-proven exchange semantics: loads sc0 sc1 (coherence-point read),
// stores relaxed-agent (__hip_atomic_store). No scope experiments.
static __device__ __forceinline__ uint4 ld_dwx4_sc(const uint32_t* p) {
    uint4 v;
    asm volatile("global_load_dwordx4 %0, %1, off sc0 sc1" : "=v"(v) : "v"(p) : "memory");
    return v;
}
static __device__ __forceinline__ uint4 ld_dwx4_pl(const void* p) {   // plain cached
    uint4 v;
    asm volatile("global_load_dwordx4 %0, %1, off" : "=v"(v) : "v"(p) : "memory");
    return v;
}
static __device__ __forceinline__ void wait_vm0() {
    asm volatile("s_waitcnt vmcnt(0)" ::: "memory");
    __builtin_amdgcn_sched_barrier(0);
}
static __device__ __forceinline__ void wait_vm2() {
    asm volatile("s_waitcnt vmcnt(2)" ::: "memory");
    __builtin_amdgcn_sched_barrier(0);
}

__global__ void sent_fill_kernel(uint32_t* w, size_t n) {
    size_t i = (size_t)blockIdx.x * blockDim.x + threadIdx.x;
    if (i < n) w[i] = SENT;
}

__global__ __launch_bounds__(256, 1) void lstm_persist(
    const float* __restrict__ x,     // [T][B][D]
    const float* __restrict__ Wx,    // [D][4H]
    const float* __restrict__ Wh,    // [H][4H]
    const float* __restrict__ bias,  // [4H]
    float* __restrict__ out,         // ys [T][B][H] + hT [B][H] + cT [B][H]
    uint32_t* __restrict__ hbuf)     // [4][B][H/2] packed bf16 pairs, SENT-initialized
{
    __shared__ __align__(16) ushort zlds[16][LDK];   // z = [x_t ; h_t], rows 8..15 zero
    __shared__ __align__(16) float gex[8][17][4];    // [batch][j(+pad)][gate i,f,g,o]

    const int tid  = threadIdx.x;          // 256 threads = 4 waves
    const int gid  = blockIdx.x & 7;       // group
    const int p    = blockIdx.x >> 3;      // block-in-group
    const int j0   = p * 16;
    const int gb   = gid * MROW;
    const int wave = tid >> 6;             // gate index 0..3
    const int lane = tid & 63;

    for (int i = tid; i < 8 * LDK; i += 256) zlds[8 + i / LDK][i % LDK] = 0;

    // weight slice -> registers (MFMA B layout)
    bf16x8 wreg[24];
    {
        const int col   = wave * HID + j0 + (lane & 15);
        const int kbase = (lane >> 4) * 8;
        #pragma unroll
        for (int ch = 0; ch < 24; ++ch) {
            bf16x8 w;
            #pragma unroll
            for (int e = 0; e < 8; ++e) {
                int k = ch * 32 + kbase + e;
                float wv = (k < DIN) ? Wx[(size_t)k * NCOL + col]
                                     : Wh[(size_t)(k - DIN) * NCOL + col];
                w[e] = (short)f2bf(wv);
            }
            wreg[ch] = w;
        }
    }
    const float biasv = bias[wave * HID + j0 + (lane & 15)];
    float c0 = 0.f, c1 = 0.f;               // c state: wave0, b=tid>>3, j=2*(tid&7)+{0,1}
    __syncthreads();

    const int xr   = tid >> 5;              // x staging row
    const int xc   = (tid & 31) * 8;        // 8 x-elems / thread
    const int arow = lane & 15;
    const int koff = (lane >> 4) * 8;
    const ushort* za = &zlds[arow][0];
    const int hr = wave * 2;                // h rows: hr, hr+1 (lane-consecutive dwords)

    // x prefetch for t=0
    uint4 xa, xb;
    {
        const float* xp = x + ((size_t)0 * NBATCH + gb + xr) * DIN + xc;
        xa = ld_dwx4_pl(xp);
        xb = ld_dwx4_pl(xp + 4);
    }

    for (int t = 0; t < T_STEPS; ++t) {
        // top-of-step: x regs ready. wave0 leaves [pub, ys] in flight (vmcnt(2));
        // they drain under the poll's h-load shadow.
        if (wave == 0 && t > 0) wait_vm2(); else wait_vm0();

        // pack x_t (bf16) -> LDS
        {
            uint4 pk;
            pk.x = (uint32_t)f2bf(__uint_as_float(xa.x)) | ((uint32_t)f2bf(__uint_as_float(xa.y)) << 16);
            pk.y = (uint32_t)f2bf(__uint_as_float(xa.z)) | ((uint32_t)f2bf(__uint_as_float(xa.w)) << 16);
            pk.z = (uint32_t)f2bf(__uint_as_float(xb.x)) | ((uint32_t)f2bf(__uint_as_float(xb.y)) << 16);
            pk.w = (uint32_t)f2bf(__uint_as_float(xb.z)) | ((uint32_t)f2bf(__uint_as_float(xb.w)) << 16);
            *(uint4*)&zlds[xr][xc] = pk;
        }
        __syncthreads();                                   // bar1

        // issue first poll-load of h_t (data IS the flag), then hide under x-MFMA
        const uint32_t* hb0 = hbuf + ((size_t)(t & 3) * NBATCH + gb + hr) * (HID / 2) + 4 * lane;
        uint4 h0, h1;
        if (t > 0) {
            h0 = ld_dwx4_sc(hb0);
            h1 = ld_dwx4_sc(hb0 + (HID / 2));
        }

        // x-part MFMAs (K = 0..255)
        f32x4 a0 = {0.f, 0.f, 0.f, 0.f};
        #pragma unroll
        for (int ch = 0; ch < 8; ++ch) {
            bf16x8 af = *(const bf16x8*)(za + ch * 32 + koff);
            a0 = __builtin_amdgcn_mfma_f32_16x16x32_bf16(af, wreg[ch], a0, 0, 0, 0);
        }

        // poll until every dword is non-sentinel (then data is already in regs)
        if (t > 0) {
            int guard = 0;
            while (true) {
                wait_vm0();
                bool ok = h0.x != SENT && h0.y != SENT && h0.z != SENT && h0.w != SENT
                       && h1.x != SENT && h1.y != SENT && h1.z != SENT && h1.w != SENT;
                if (__all((int)ok)) break;
                if (++guard > (1 << 17)) break;            // hang safety
                h0 = ld_dwx4_sc(hb0);
                h1 = ld_dwx4_sc(hb0 + (HID / 2));
            }
            *(uint4*)&zlds[hr][DIN + 8 * lane]     = h0;
            *(uint4*)&zlds[hr + 1][DIN + 8 * lane] = h1;
        } else {
            uint4 z4 = {0u, 0u, 0u, 0u};                   // h_0 = 0
            *(uint4*)&zlds[hr][DIN + 8 * lane]     = z4;
            *(uint4*)&zlds[hr + 1][DIN + 8 * lane] = z4;
        }

        // early sentinel-reset of buf[(t+2)&3] own slice (drained by publish vmcnt)
        if (tid < 64) {
            const int b = tid >> 3, jp = tid & 7;
            __hip_atomic_store(hbuf + ((size_t)((t + 2) & 3) * NBATCH + gb + b) * (HID / 2)
                               + (j0 >> 1) + jp, SENT,
                               __ATOMIC_RELAXED, __HIP_MEMORY_SCOPE_AGENT);
        }
        // x prefetch for t+1 (newest; kept in flight across publish)
        {
            int tn = (t + 1 < T_STEPS) ? t + 1 : t;
            const float* xp = x + ((size_t)tn * NBATCH + gb + xr) * DIN + xc;
            xa = ld_dwx4_pl(xp);
            xb = ld_dwx4_pl(xp + 4);
        }
        __syncthreads();                                   // bar3

        // h-part MFMAs (K = 256..767), four chains
        f32x4 a1 = {0.f, 0.f, 0.f, 0.f};
        f32x4 a2 = {0.f, 0.f, 0.f, 0.f};
        f32x4 a3 = {0.f, 0.f, 0.f, 0.f};
        f32x4 a4 = {0.f, 0.f, 0.f, 0.f};
        #pragma unroll
        for (int ch = 8; ch < 12; ++ch) {
            bf16x8 af = *(const bf16x8*)(za + ch * 32 + koff);
            a1 = __builtin_amdgcn_mfma_f32_16x16x32_bf16(af, wreg[ch], a1, 0, 0, 0);
        }
        #pragma unroll
        for (int ch = 12; ch < 16; ++ch) {
            bf16x8 af = *(const bf16x8*)(za + ch * 32 + koff);
            a2 = __builtin_amdgcn_mfma_f32_16x16x32_bf16(af, wreg[ch], a2, 0, 0, 0);
        }
        #pragma unroll
        for (int ch = 16; ch < 20; ++ch) {
            bf16x8 af = *(const bf16x8*)(za + ch * 32 + koff);
            a3 = __builtin_amdgcn_mfma_f32_16x16x32_bf16(af, wreg[ch], a3, 0, 0, 0);
        }
        #pragma unroll
        for (int ch = 20; ch < 24; ++ch) {
            bf16x8 af = *(const bf16x8*)(za + ch * 32 + koff);
            a4 = __builtin_amdgcn_mfma_f32_16x16x32_bf16(af, wreg[ch], a4, 0, 0, 0);
        }
        f32x4 acc = ((a0 + a1) + (a2 + a3)) + a4;

        // gate exchange: acc row=(lane>>4)*4+r (batch), col=lane&15 (j)
        if (lane < 32) {
            int r0 = (lane >> 4) * 4, col = lane & 15;
            #pragma unroll
            for (int r = 0; r < 4; ++r)
                gex[r0 + r][col][wave] = acc[r] + biasv;
        }
        __syncthreads();                                   // bar4

        // wave 0: cell update; publish h_{t+1} fire-and-forget (data is the flag)
        if (tid < 64) {
            const int b = tid >> 3, jp = tid & 7, j = jp * 2;
            f32x4 ga = *(const f32x4*)&gex[b][j][0];
            f32x4 gc = *(const f32x4*)&gex[b][j + 1][0];
            float i0 = sigm(ga[0]), f0 = sigm(ga[1]), g0 = tanh_fast(ga[2]), o0 = sigm(ga[3]);
            float i1 = sigm(gc[0]), f1 = sigm(gc[1]), g1 = tanh_fast(gc[2]), o1 = sigm(gc[3]);
            c0 = f0 * c0 + i0 * g0;
            c1 = f1 * c1 + i1 * g1;
            float h0v = o0 * tanh_fast(c0);
            float h1v = o1 * tanh_fast(c1);

            // outstanding (oldest first): [reset, xa, xb] -> vmcnt(2) drains reset
            // (ordering: this buffer's sentinel must be performed before any
            //  h-data that transitively licenses a consumer to re-poll it)
            wait_vm2();

            uint32_t pkh = (uint32_t)f2bf(h0v) | ((uint32_t)f2bf(h1v) << 16);
            __hip_atomic_store(hbuf + ((size_t)((t + 1) & 3) * NBATCH + gb + b) * (HID / 2)
                               + (j0 >> 1) + jp, pkh,
                               __ATOMIC_RELAXED, __HIP_MEMORY_SCOPE_AGENT);

            // ys output after publish (not on the protocol's critical path)
            float2 hv = {h0v, h1v};
            *(float2*)(out + ((size_t)t * NBATCH + gb + b) * HID + j0 + j) = hv;
            if (t == T_STEPS - 1) {
                float* hTp = out + (size_t)T_STEPS * NBATCH * HID
                             + (size_t)(gb + b) * HID + j0 + j;
                float2 cv = {c0, c1};
                *(float2*)hTp = hv;
                *(float2*)(hTp + (size_t)NBATCH * HID) = cv;
            }
        }
        // no trailing barrier: bar1 re-syncs
    }
}

extern "C" void kernel_launch(void* const* d_in, const int* in_sizes, int n_in,
                              void* d_out, int out_size, void* d_ws, size_t ws_size,
                              hipStream_t stream) {
    const float* x    = (const float*)d_in[0];
    const float* Wx   = (const float*)d_in[1];
    const float* Wh   = (const float*)d_in[2];
    const float* bias = (const float*)d_in[3];
    float* out = (float*)d_out;

    uint32_t* hbuf = (uint32_t*)d_ws;                  // [4][64][256] dwords = 256 KB

    {
        size_t n = HBUF_DWORDS;
        int blocks = (int)((n + 255) / 256);
        sent_fill_kernel<<<dim3(blocks), dim3(256), 0, stream>>>(hbuf, n);
    }
    lstm_persist<<<dim3(NGRP * BPG), dim3(256), 0, stream>>>(x, Wx, Wh, bias, out, hbuf);
}